// Round 32
// baseline (8486.022 us; speedup 1.0000x reference)
//
#include <hip/hip_runtime.h>

#define LOG2E 1.44269504088896340736f

__device__ __forceinline__ float lrelu(float z) { return fmaxf(z, 0.01f * z); }
__device__ __forceinline__ float sigf(float z) {
    float p = __builtin_amdgcn_exp2f(-LOG2E * z);
    return __builtin_amdgcn_rcpf(1.0f + p);
}

#define WQ(i) __int_as_float(__builtin_amdgcn_readlane(__float_as_int(wreg[(i) >> 6]), (i) & 63))

// ====== PC-v12: pc8 + 2-step phases (barrier halving + X weight amortization)
// R31: v2f pk-fma regressed (compiler scalarized; VGPR 220, VALUBusy 37%).
// pc8 residual = barrier overhead (512 syncs) + alternation. This round:
// one barrier per 2 steps (257 total). F runs 2 sequential steps per phase
// (no amortization possible - true dep). X computes BOTH lagged steps in one
// block: each weight read once per 4 outputs (2 steps x 2 points) - X RL and
// LDS traffic halve, NO cross-barrier state (R30's failure mode avoided).
// Ring: F writes slots 2p&3,(2p+1)&3; X reads (2p-2)&3,(2p-1)&3 (disjoint
// mod 4; overwrite ordered by phase barrier). F identical per-step to pc8
// (wv[140] pin); X drops pin (rows 39..45 via uniform L2, amortized).
__global__ void __launch_bounds__(256, 1)
pc12_kernel(const float* __restrict__ w,
            const float* __restrict__ Wh1, const float* __restrict__ bh1,
            const float* __restrict__ Wh2, const float* __restrict__ bh2,
            const float* __restrict__ Wh3, const float* __restrict__ bh3,
            const float* __restrict__ Wx1, const float* __restrict__ bx1,
            const float* __restrict__ Wx2, const float* __restrict__ bx2,
            const float* __restrict__ Wx3, const float* __restrict__ bx3,
            float2* __restrict__ out, int B, int T)
{
    __shared__ float4 sW2h[185];       // Wh2 rows 0..36
    __shared__ float4 sW2x[195];       // Wx2 rows 0..38
    __shared__ float2 hbuf[4][256];    // 4-deep ring

    {
        float* a = (float*)sW2h;
        for (int i = threadIdx.x; i < 740; i += 256) a[i] = Wh2[i];
        float* b = (float*)sW2x;
        for (int i = threadIdx.x; i < 780; i += 256) b[i] = Wx2[i];
    }

    const int wid  = threadIdx.x >> 6;     // 0..3
    const int lane = threadIdx.x & 63;
    const bool is_f = (wid < 2);

    float wreg[6];
    float wv[140];   // F-only soft pin (pc8 mechanism)
    if (is_f) {
#pragma unroll
        for (int r = 0; r < 6; ++r) {
            const int idx = r * 64 + lane;
            float v = 0.f;
            if      (idx < 100) v = Wh1[idx];
            else if (idx < 150) v = bh1[idx - 100];
            else if (idx < 270) v = Wh2[880 + (idx - 150)];   // rows 44..49
            else if (idx < 290) v = bh2[idx - 270];
            else if (idx < 330) v = Wh3[idx - 290];
            else if (idx < 332) v = bh3[idx - 330];
            wreg[r] = v;
        }
#pragma unroll
        for (int i = 0; i < 140; ++i) {        // pin Wh2 rows 37..43
            wv[i] = Wh2[740 + i];
            asm volatile("" : "+v"(wv[i]));
        }
    } else {
#pragma unroll
        for (int r = 0; r < 6; ++r) {
            const int idx = r * 64 + lane;
            float v = 0.f;
            if      (idx < 100) v = Wx1[idx];
            else if (idx < 150) v = bx1[idx - 100];
            else if (idx < 230) v = Wx2[920 + (idx - 150)];   // rows 46..49
            else if (idx < 250) v = bx2[idx - 230];
            else if (idx < 290) v = Wx3[idx - 250];
            else if (idx < 292) v = bx3[idx - 290];
            wreg[r] = v;
        }
    }
    __syncthreads();

    const int lw = is_f ? wid : (wid - 2);
    const int lpA = lw * 128 + lane;
    const int lpB = lpA + 64;
    const int pA  = blockIdx.x * 256 + lpA;
    const int pB  = blockIdx.x * 256 + lpB;

    float hA0 = 0.f, hA1 = 0.f, hB0 = 0.f, hB1 = 0.f;
    if (is_f) {
        hA0 = w[2 * pA]; hA1 = w[2 * pA + 1];
        hB0 = w[2 * pB]; hB1 = w[2 * pB + 1];
    }
    float2* __restrict__ orowA = out + (size_t)pA * (size_t)T;
    float2* __restrict__ orowB = out + (size_t)pB * (size_t)T;

    const float* __restrict__ gWx2 = Wx2 + 780;   // rows 39..45 (uniform L2)

    const int P = T / 2;   // phases 0..P
    for (int p = 0; p <= P; ++p) {
        if (is_f) {
            if (p < P) {
                // ===== F: two sequential steps t = 2p, 2p+1 =====
                for (int half = 0; half < 2; ++half) {
                    const int t = 2 * p + half;
                    float a1A[50], a1B[50];
#pragma unroll
                    for (int j = 0; j < 50; ++j) {
                        const float s0 = WQ(j), s1 = WQ(50 + j), sb = WQ(100 + j);
                        a1A[j] = lrelu(fmaf(hA0, s0, fmaf(hA1, s1, sb)));
                        a1B[j] = lrelu(fmaf(hB0, s0, fmaf(hB1, s1, sb)));
                    }
                    float accA[20], accB[20];
#pragma unroll
                    for (int c = 0; c < 20; ++c) {
                        const float bv = WQ(270 + c);
                        accA[c] = bv; accB[c] = bv;
                    }
#pragma unroll
                    for (int k = 0; k < 37; ++k) {      // rows 0..36 via LDS
                        const float akA = a1A[k], akB = a1B[k];
#pragma unroll
                        for (int c = 0; c < 5; ++c) {
                            const float4 v = sW2h[k * 5 + c];
                            accA[4*c+0] = fmaf(akA, v.x, accA[4*c+0]);
                            accA[4*c+1] = fmaf(akA, v.y, accA[4*c+1]);
                            accA[4*c+2] = fmaf(akA, v.z, accA[4*c+2]);
                            accA[4*c+3] = fmaf(akA, v.w, accA[4*c+3]);
                            accB[4*c+0] = fmaf(akB, v.x, accB[4*c+0]);
                            accB[4*c+1] = fmaf(akB, v.y, accB[4*c+1]);
                            accB[4*c+2] = fmaf(akB, v.z, accB[4*c+2]);
                            accB[4*c+3] = fmaf(akB, v.w, accB[4*c+3]);
                        }
                    }
#pragma unroll
                    for (int k = 37; k < 44; ++k) {     // rows 37..43 via pin
                        const float akA = a1A[k], akB = a1B[k];
#pragma unroll
                        for (int c = 0; c < 20; ++c) {
                            const float wvv = wv[(k - 37) * 20 + c];
                            accA[c] = fmaf(akA, wvv, accA[c]);
                            accB[c] = fmaf(akB, wvv, accB[c]);
                        }
                    }
#pragma unroll
                    for (int k = 44; k < 50; ++k) {     // rows 44..49 via RL
                        const float akA = a1A[k], akB = a1B[k];
#pragma unroll
                        for (int c = 0; c < 20; ++c) {
                            const float wvv = WQ(150 + (k - 44) * 20 + c);
                            accA[c] = fmaf(akA, wvv, accA[c]);
                            accB[c] = fmaf(akB, wvv, accB[c]);
                        }
                    }
                    float zA0 = WQ(330), zA1 = WQ(331);
                    float zB0 = zA0, zB1 = zA1;
#pragma unroll
                    for (int k = 0; k < 20; ++k) {
                        const float wx = WQ(290 + 2 * k), wy = WQ(291 + 2 * k);
                        const float eA = lrelu(accA[k]), eB = lrelu(accB[k]);
                        zA0 = fmaf(eA, wx, zA0); zA1 = fmaf(eA, wy, zA1);
                        zB0 = fmaf(eB, wx, zB0); zB1 = fmaf(eB, wy, zB1);
                    }
                    hA0 = lrelu(zA0); hA1 = lrelu(zA1);
                    hB0 = lrelu(zB0); hB1 = lrelu(zB1);

                    hbuf[t & 3][lpA] = make_float2(hA0, hA1);
                    hbuf[t & 3][lpB] = make_float2(hB0, hB1);
                }
            }
        } else {
            if (p >= 1) {
                // ===== X: steps s0 = 2p-2, s1 = 2p-1; weights read once =====
                const int s0i = 2 * p - 2, s1i = 2 * p - 1;
                const float2 h0A = hbuf[s0i & 3][lpA];
                const float2 h1A = hbuf[s1i & 3][lpA];
                const float2 h0B = hbuf[s0i & 3][lpB];
                const float2 h1B = hbuf[s1i & 3][lpB];

                float acc0A[20], acc0B[20], acc1A[20], acc1B[20];
#pragma unroll
                for (int c = 0; c < 20; ++c) {
                    const float bv = WQ(230 + c);
                    acc0A[c] = bv; acc0B[c] = bv; acc1A[c] = bv; acc1B[c] = bv;
                }
#pragma unroll
                for (int k = 0; k < 50; ++k) {
                    const float s0 = WQ(k), s1 = WQ(50 + k), sb = WQ(100 + k);
                    const float xk0A = sigf(fmaf(h0A.x, s0, fmaf(h0A.y, s1, sb)));
                    const float xk0B = sigf(fmaf(h0B.x, s0, fmaf(h0B.y, s1, sb)));
                    const float xk1A = sigf(fmaf(h1A.x, s0, fmaf(h1A.y, s1, sb)));
                    const float xk1B = sigf(fmaf(h1B.x, s0, fmaf(h1B.y, s1, sb)));
                    if (k < 39) {                        // rows 0..38 via LDS
#pragma unroll
                        for (int c4 = 0; c4 < 5; ++c4) {
                            const float4 v = sW2x[k * 5 + c4];
                            acc0A[4*c4+0] = fmaf(xk0A, v.x, acc0A[4*c4+0]);
                            acc0A[4*c4+1] = fmaf(xk0A, v.y, acc0A[4*c4+1]);
                            acc0A[4*c4+2] = fmaf(xk0A, v.z, acc0A[4*c4+2]);
                            acc0A[4*c4+3] = fmaf(xk0A, v.w, acc0A[4*c4+3]);
                            acc0B[4*c4+0] = fmaf(xk0B, v.x, acc0B[4*c4+0]);
                            acc0B[4*c4+1] = fmaf(xk0B, v.y, acc0B[4*c4+1]);
                            acc0B[4*c4+2] = fmaf(xk0B, v.z, acc0B[4*c4+2]);
                            acc0B[4*c4+3] = fmaf(xk0B, v.w, acc0B[4*c4+3]);
                            acc1A[4*c4+0] = fmaf(xk1A, v.x, acc1A[4*c4+0]);
                            acc1A[4*c4+1] = fmaf(xk1A, v.y, acc1A[4*c4+1]);
                            acc1A[4*c4+2] = fmaf(xk1A, v.z, acc1A[4*c4+2]);
                            acc1A[4*c4+3] = fmaf(xk1A, v.w, acc1A[4*c4+3]);
                            acc1B[4*c4+0] = fmaf(xk1B, v.x, acc1B[4*c4+0]);
                            acc1B[4*c4+1] = fmaf(xk1B, v.y, acc1B[4*c4+1]);
                            acc1B[4*c4+2] = fmaf(xk1B, v.z, acc1B[4*c4+2]);
                            acc1B[4*c4+3] = fmaf(xk1B, v.w, acc1B[4*c4+3]);
                        }
                    } else if (k < 46) {                 // rows 39..45 via L2
#pragma unroll
                        for (int c = 0; c < 20; ++c) {
                            const float wvv = gWx2[(k - 39) * 20 + c];
                            acc0A[c] = fmaf(xk0A, wvv, acc0A[c]);
                            acc0B[c] = fmaf(xk0B, wvv, acc0B[c]);
                            acc1A[c] = fmaf(xk1A, wvv, acc1A[c]);
                            acc1B[c] = fmaf(xk1B, wvv, acc1B[c]);
                        }
                    } else {                             // rows 46..49 via RL
#pragma unroll
                        for (int c = 0; c < 20; ++c) {
                            const float wvv = WQ(150 + (k - 46) * 20 + c);
                            acc0A[c] = fmaf(xk0A, wvv, acc0A[c]);
                            acc0B[c] = fmaf(xk0B, wvv, acc0B[c]);
                            acc1A[c] = fmaf(xk1A, wvv, acc1A[c]);
                            acc1B[c] = fmaf(xk1B, wvv, acc1B[c]);
                        }
                    }
                }
                float z00A = WQ(290), z10A = WQ(291);
                float z00B = z00A, z10B = z10A;
                float z01A = z00A, z11A = z10A;
                float z01B = z00A, z11B = z10A;
#pragma unroll
                for (int k = 0; k < 20; ++k) {
                    const float wx = WQ(250 + 2 * k), wy = WQ(251 + 2 * k);
                    const float e0A = sigf(acc0A[k]), e0B = sigf(acc0B[k]);
                    const float e1A = sigf(acc1A[k]), e1B = sigf(acc1B[k]);
                    z00A = fmaf(e0A, wx, z00A); z10A = fmaf(e0A, wy, z10A);
                    z00B = fmaf(e0B, wx, z00B); z10B = fmaf(e0B, wy, z10B);
                    z01A = fmaf(e1A, wx, z01A); z11A = fmaf(e1A, wy, z11A);
                    z01B = fmaf(e1B, wx, z01B); z11B = fmaf(e1B, wy, z11B);
                }
                orowA[s0i] = make_float2(sigf(z00A), sigf(z10A));
                orowB[s0i] = make_float2(sigf(z00B), sigf(z10B));
                orowA[s1i] = make_float2(sigf(z01A), sigf(z11A));
                orowB[s1i] = make_float2(sigf(z01B), sigf(z11B));
            }
        }
        __syncthreads();   // one barrier per 2 steps; orders ring reuse
    }
}

extern "C" void kernel_launch(void* const* d_in, const int* in_sizes, int n_in,
                              void* d_out, int out_size, void* d_ws, size_t ws_size,
                              hipStream_t stream)
{
    const float* w   = (const float*)d_in[0];
    const float* Wh1 = (const float*)d_in[1];
    const float* bh1 = (const float*)d_in[2];
    const float* Wh2 = (const float*)d_in[3];
    const float* bh2 = (const float*)d_in[4];
    const float* Wh3 = (const float*)d_in[5];
    const float* bh3 = (const float*)d_in[6];
    const float* Wx1 = (const float*)d_in[7];
    const float* bx1 = (const float*)d_in[8];
    const float* Wx2 = (const float*)d_in[9];
    const float* bx2 = (const float*)d_in[10];
    const float* Wx3 = (const float*)d_in[11];
    const float* bx3 = (const float*)d_in[12];

    const int B = in_sizes[0] / 2;        // 65536 (divisible by 256)
    const int T = out_size / (B * 2);     // 512 (even)

    pc12_kernel<<<B / 256, 256, 0, stream>>>(
        w, Wh1, bh1, Wh2, bh2, Wh3, bh3,
        Wx1, bx1, Wx2, bx2, Wx3, bx3,
        (float2*)d_out, B, T);
}

// Round 33
// 3532.483 us; speedup vs baseline: 2.4023x; 2.4023x over previous
//
#include <hip/hip_runtime.h>

#define LOG2E 1.44269504088896340736f

__device__ __forceinline__ float lrelu(float z) { return fmaxf(z, 0.01f * z); }
__device__ __forceinline__ float sigf(float z) {
    float p = __builtin_amdgcn_exp2f(-LOG2E * z);
    return __builtin_amdgcn_rcpf(1.0f + p);
}

#define WQ(i) __int_as_float(__builtin_amdgcn_readlane(__float_as_int(wreg[(i) >> 6]), (i) & 63))

// ====== PC-v8 (FINAL): measured best at 3.53 ms (R28) ======
// Producer-consumer: 2 F-waves (recurrence) + 2 X-waves (output map, one step
// behind via double-buffered LDS handoff), 2 points/thread, broadcasts shared.
// Weight-broadcast path mix (converged over R10-R32):
//   per wave: LDS uniform ds_read_b128 (W2 bulk) + partial VGPR pin (140
//   floats via asm "+v"; compiler keeps ~half resident, rest become cheap
//   uniform L2 loads) + readlane for the remainder.
// Structure/schedule variants all regressed: stagger (R29), X-batching
// (R30/R32, spills), pk-fma (R31, scalarized), SGB-pinned prefetch (R23,
// honored but null), occupancy raises (R15/R17/R18, broadcast conservation
// + spill). Three pipes balanced: LDS ~9.1K, F/X VALU ~7.8K cyc/step.
__global__ void __launch_bounds__(256, 1)
pc8_kernel(const float* __restrict__ w,
           const float* __restrict__ Wh1, const float* __restrict__ bh1,
           const float* __restrict__ Wh2, const float* __restrict__ bh2,
           const float* __restrict__ Wh3, const float* __restrict__ bh3,
           const float* __restrict__ Wx1, const float* __restrict__ bx1,
           const float* __restrict__ Wx2, const float* __restrict__ bx2,
           const float* __restrict__ Wx3, const float* __restrict__ bx3,
           float2* __restrict__ out, int B, int T)
{
    __shared__ float4 sW2h[185];       // Wh2 rows 0..36
    __shared__ float4 sW2x[195];       // Wx2 rows 0..38
    __shared__ float2 hbuf[2][256];    // double-buffered h handoff

    {
        float* a = (float*)sW2h;
        for (int i = threadIdx.x; i < 740; i += 256) a[i] = Wh2[i];
        float* b = (float*)sW2x;
        for (int i = threadIdx.x; i < 780; i += 256) b[i] = Wx2[i];
    }

    const int wid  = threadIdx.x >> 6;     // 0..3
    const int lane = threadIdx.x & 63;
    const bool is_f = (wid < 2);

    float wreg[6];
    float wv[140];   // partial VGPR pin (R25 mechanism)
    if (is_f) {
#pragma unroll
        for (int r = 0; r < 6; ++r) {
            const int idx = r * 64 + lane;
            float v = 0.f;
            if      (idx < 100) v = Wh1[idx];
            else if (idx < 150) v = bh1[idx - 100];
            else if (idx < 270) v = Wh2[880 + (idx - 150)];   // rows 44..49
            else if (idx < 290) v = bh2[idx - 270];
            else if (idx < 330) v = Wh3[idx - 290];
            else if (idx < 332) v = bh3[idx - 330];
            wreg[r] = v;
        }
#pragma unroll
        for (int i = 0; i < 140; ++i) {        // pin Wh2 rows 37..43
            wv[i] = Wh2[740 + i];
            asm volatile("" : "+v"(wv[i]));
        }
    } else {
#pragma unroll
        for (int r = 0; r < 6; ++r) {
            const int idx = r * 64 + lane;
            float v = 0.f;
            if      (idx < 100) v = Wx1[idx];
            else if (idx < 150) v = bx1[idx - 100];
            else if (idx < 230) v = Wx2[920 + (idx - 150)];   // rows 46..49
            else if (idx < 250) v = bx2[idx - 230];
            else if (idx < 290) v = Wx3[idx - 250];
            else if (idx < 292) v = bx3[idx - 290];
            wreg[r] = v;
        }
#pragma unroll
        for (int i = 0; i < 140; ++i) {        // pin Wx2 rows 39..45
            wv[i] = Wx2[780 + i];
            asm volatile("" : "+v"(wv[i]));
        }
    }
    __syncthreads();

    const int lw = is_f ? wid : (wid - 2);
    const int lpA = lw * 128 + lane;
    const int lpB = lpA + 64;
    const int pA  = blockIdx.x * 256 + lpA;
    const int pB  = blockIdx.x * 256 + lpB;

    float hA0 = 0.f, hA1 = 0.f, hB0 = 0.f, hB1 = 0.f;
    if (is_f) {
        hA0 = w[2 * pA]; hA1 = w[2 * pA + 1];
        hB0 = w[2 * pB]; hB1 = w[2 * pB + 1];
    }
    float2* __restrict__ orowA = out + (size_t)pA * (size_t)T;
    float2* __restrict__ orowB = out + (size_t)pB * (size_t)T;

    for (int t = 0; t <= T; ++t) {
        if (is_f) {
            if (t < T) {
                // ===== F: h = lrelu3(h), 2 points, broadcasts shared =====
                float a1A[50], a1B[50];
#pragma unroll
                for (int j = 0; j < 50; ++j) {
                    const float s0 = WQ(j), s1 = WQ(50 + j), sb = WQ(100 + j);
                    a1A[j] = lrelu(fmaf(hA0, s0, fmaf(hA1, s1, sb)));
                    a1B[j] = lrelu(fmaf(hB0, s0, fmaf(hB1, s1, sb)));
                }
                float accA[20], accB[20];
#pragma unroll
                for (int c = 0; c < 20; ++c) {
                    const float bv = WQ(270 + c);
                    accA[c] = bv; accB[c] = bv;
                }
#pragma unroll
                for (int k = 0; k < 37; ++k) {          // rows 0..36 via LDS
                    const float akA = a1A[k], akB = a1B[k];
#pragma unroll
                    for (int c = 0; c < 5; ++c) {
                        const float4 v = sW2h[k * 5 + c];
                        accA[4*c+0] = fmaf(akA, v.x, accA[4*c+0]);
                        accA[4*c+1] = fmaf(akA, v.y, accA[4*c+1]);
                        accA[4*c+2] = fmaf(akA, v.z, accA[4*c+2]);
                        accA[4*c+3] = fmaf(akA, v.w, accA[4*c+3]);
                        accB[4*c+0] = fmaf(akB, v.x, accB[4*c+0]);
                        accB[4*c+1] = fmaf(akB, v.y, accB[4*c+1]);
                        accB[4*c+2] = fmaf(akB, v.z, accB[4*c+2]);
                        accB[4*c+3] = fmaf(akB, v.w, accB[4*c+3]);
                    }
                }
#pragma unroll
                for (int k = 37; k < 44; ++k) {         // rows 37..43 via pin
                    const float akA = a1A[k], akB = a1B[k];
#pragma unroll
                    for (int c = 0; c < 20; ++c) {
                        const float wvv = wv[(k - 37) * 20 + c];
                        accA[c] = fmaf(akA, wvv, accA[c]);
                        accB[c] = fmaf(akB, wvv, accB[c]);
                    }
                }
#pragma unroll
                for (int k = 44; k < 50; ++k) {         // rows 44..49 via RL
                    const float akA = a1A[k], akB = a1B[k];
#pragma unroll
                    for (int c = 0; c < 20; ++c) {
                        const float wvv = WQ(150 + (k - 44) * 20 + c);
                        accA[c] = fmaf(akA, wvv, accA[c]);
                        accB[c] = fmaf(akB, wvv, accB[c]);
                    }
                }
                float zA0 = WQ(330), zA1 = WQ(331);
                float zB0 = zA0, zB1 = zA1;
#pragma unroll
                for (int k = 0; k < 20; ++k) {
                    const float wx = WQ(290 + 2 * k), wy = WQ(291 + 2 * k);
                    const float eA = lrelu(accA[k]), eB = lrelu(accB[k]);
                    zA0 = fmaf(eA, wx, zA0); zA1 = fmaf(eA, wy, zA1);
                    zB0 = fmaf(eB, wx, zB0); zB1 = fmaf(eB, wy, zB1);
                }
                hA0 = lrelu(zA0); hA1 = lrelu(zA1);
                hB0 = lrelu(zB0); hB1 = lrelu(zB1);

                hbuf[t & 1][lpA] = make_float2(hA0, hA1);
                hbuf[t & 1][lpB] = make_float2(hB0, hB1);
            }
        } else {
            if (t > 0) {
                // ===== X: x_s = sig3(h_s), s = t-1, 2 points =====
                const int s = t - 1;
                const float2 hvA = hbuf[s & 1][lpA];
                const float2 hvB = hbuf[s & 1][lpB];

                float accA[20], accB[20];
#pragma unroll
                for (int c = 0; c < 20; ++c) {
                    const float bv = WQ(230 + c);
                    accA[c] = bv; accB[c] = bv;
                }
#pragma unroll
                for (int k = 0; k < 50; ++k) {
                    // Wx1-trip via RL (off the binding LDS pipe)
                    const float s0 = WQ(k), s1 = WQ(50 + k), sb = WQ(100 + k);
                    const float xkA = sigf(fmaf(hvA.x, s0, fmaf(hvA.y, s1, sb)));
                    const float xkB = sigf(fmaf(hvB.x, s0, fmaf(hvB.y, s1, sb)));
                    if (k < 39) {                        // rows 0..38 via LDS
#pragma unroll
                        for (int c = 0; c < 5; ++c) {
                            const float4 v = sW2x[k * 5 + c];
                            accA[4*c+0] = fmaf(xkA, v.x, accA[4*c+0]);
                            accA[4*c+1] = fmaf(xkA, v.y, accA[4*c+1]);
                            accA[4*c+2] = fmaf(xkA, v.z, accA[4*c+2]);
                            accA[4*c+3] = fmaf(xkA, v.w, accA[4*c+3]);
                            accB[4*c+0] = fmaf(xkB, v.x, accB[4*c+0]);
                            accB[4*c+1] = fmaf(xkB, v.y, accB[4*c+1]);
                            accB[4*c+2] = fmaf(xkB, v.z, accB[4*c+2]);
                            accB[4*c+3] = fmaf(xkB, v.w, accB[4*c+3]);
                        }
                    } else if (k < 46) {                 // rows 39..45 via pin
#pragma unroll
                        for (int c = 0; c < 20; ++c) {
                            const float wvv = wv[(k - 39) * 20 + c];
                            accA[c] = fmaf(xkA, wvv, accA[c]);
                            accB[c] = fmaf(xkB, wvv, accB[c]);
                        }
                    } else {                             // rows 46..49 via RL
#pragma unroll
                        for (int c = 0; c < 20; ++c) {
                            const float wvv = WQ(150 + (k - 46) * 20 + c);
                            accA[c] = fmaf(xkA, wvv, accA[c]);
                            accB[c] = fmaf(xkB, wvv, accB[c]);
                        }
                    }
                }
                float zA0 = WQ(290), zA1 = WQ(291);
                float zB0 = zA0, zB1 = zA1;
#pragma unroll
                for (int k = 0; k < 20; ++k) {
                    const float wx = WQ(250 + 2 * k), wy = WQ(251 + 2 * k);
                    const float eA = sigf(accA[k]), eB = sigf(accB[k]);
                    zA0 = fmaf(eA, wx, zA0); zA1 = fmaf(eA, wy, zA1);
                    zB0 = fmaf(eB, wx, zB0); zB1 = fmaf(eB, wy, zB1);
                }
                orowA[s] = make_float2(sigf(zA0), sigf(zA1));
                orowB[s] = make_float2(sigf(zB0), sigf(zB1));
            }
        }
        __syncthreads();   // orders hbuf write (iter t) -> read (iter t+1)
    }
}

extern "C" void kernel_launch(void* const* d_in, const int* in_sizes, int n_in,
                              void* d_out, int out_size, void* d_ws, size_t ws_size,
                              hipStream_t stream)
{
    const float* w   = (const float*)d_in[0];
    const float* Wh1 = (const float*)d_in[1];
    const float* bh1 = (const float*)d_in[2];
    const float* Wh2 = (const float*)d_in[3];
    const float* bh2 = (const float*)d_in[4];
    const float* Wh3 = (const float*)d_in[5];
    const float* bh3 = (const float*)d_in[6];
    const float* Wx1 = (const float*)d_in[7];
    const float* bx1 = (const float*)d_in[8];
    const float* Wx2 = (const float*)d_in[9];
    const float* bx2 = (const float*)d_in[10];
    const float* Wx3 = (const float*)d_in[11];
    const float* bx3 = (const float*)d_in[12];

    const int B = in_sizes[0] / 2;        // 65536 (divisible by 256)
    const int T = out_size / (B * 2);     // 512

    pc8_kernel<<<B / 256, 256, 0, stream>>>(
        w, Wh1, bh1, Wh2, bh2, Wh3, bh3,
        Wx1, bx1, Wx2, bx2, Wx3, bx3,
        (float2*)d_out, B, T);
}

// Round 34
// 3531.224 us; speedup vs baseline: 2.4031x; 1.0004x over previous
//
#include <hip/hip_runtime.h>

#define LOG2E 1.44269504088896340736f

__device__ __forceinline__ float lrelu(float z) { return fmaxf(z, 0.01f * z); }
__device__ __forceinline__ float sigf(float z) {
    float p = __builtin_amdgcn_exp2f(-LOG2E * z);
    return __builtin_amdgcn_rcpf(1.0f + p);
}

#define WQ(i) __int_as_float(__builtin_amdgcn_readlane(__float_as_int(wreg[(i) >> 6]), (i) & 63))

// Barrier WITHOUT the vmcnt(0) drain: the loop's only cross-wave dependence
// is hbuf (LDS), so lgkmcnt(0) + s_barrier is sufficient. __syncthreads()
// additionally drains vmcnt(0), putting X's 2 end-of-iter global stores'
// L2-ack (~200-400cyc) on the critical path of all 512 iterations for free.
__device__ __forceinline__ void lds_barrier() {
    asm volatile("s_waitcnt lgkmcnt(0)" ::: "memory");
    __builtin_amdgcn_s_barrier();
}

// ====== PC-v13: pc8 (3.53ms) + lgkmcnt-only barrier ======
// pc8 converged over R10-R33: PC structure (2 F-waves recurrence + 2 X-waves
// output map via double-buffered LDS handoff, 2pt/thread, broadcast mix
// LDS/pin/RL). All schedule/path variants regressed. Last mechanism: remove
// the __syncthreads vmcnt(0) store-drain (m97-documented stall source).
__global__ void __launch_bounds__(256, 1)
pc13_kernel(const float* __restrict__ w,
            const float* __restrict__ Wh1, const float* __restrict__ bh1,
            const float* __restrict__ Wh2, const float* __restrict__ bh2,
            const float* __restrict__ Wh3, const float* __restrict__ bh3,
            const float* __restrict__ Wx1, const float* __restrict__ bx1,
            const float* __restrict__ Wx2, const float* __restrict__ bx2,
            const float* __restrict__ Wx3, const float* __restrict__ bx3,
            float2* __restrict__ out, int B, int T)
{
    __shared__ float4 sW2h[185];       // Wh2 rows 0..36
    __shared__ float4 sW2x[195];       // Wx2 rows 0..38
    __shared__ float2 hbuf[2][256];    // double-buffered h handoff

    {
        float* a = (float*)sW2h;
        for (int i = threadIdx.x; i < 740; i += 256) a[i] = Wh2[i];
        float* b = (float*)sW2x;
        for (int i = threadIdx.x; i < 780; i += 256) b[i] = Wx2[i];
    }

    const int wid  = threadIdx.x >> 6;     // 0..3
    const int lane = threadIdx.x & 63;
    const bool is_f = (wid < 2);

    float wreg[6];
    float wv[140];   // partial VGPR pin (R25 mechanism)
    if (is_f) {
#pragma unroll
        for (int r = 0; r < 6; ++r) {
            const int idx = r * 64 + lane;
            float v = 0.f;
            if      (idx < 100) v = Wh1[idx];
            else if (idx < 150) v = bh1[idx - 100];
            else if (idx < 270) v = Wh2[880 + (idx - 150)];   // rows 44..49
            else if (idx < 290) v = bh2[idx - 270];
            else if (idx < 330) v = Wh3[idx - 290];
            else if (idx < 332) v = bh3[idx - 330];
            wreg[r] = v;
        }
#pragma unroll
        for (int i = 0; i < 140; ++i) {        // pin Wh2 rows 37..43
            wv[i] = Wh2[740 + i];
            asm volatile("" : "+v"(wv[i]));
        }
    } else {
#pragma unroll
        for (int r = 0; r < 6; ++r) {
            const int idx = r * 64 + lane;
            float v = 0.f;
            if      (idx < 100) v = Wx1[idx];
            else if (idx < 150) v = bx1[idx - 100];
            else if (idx < 230) v = Wx2[920 + (idx - 150)];   // rows 46..49
            else if (idx < 250) v = bx2[idx - 230];
            else if (idx < 290) v = Wx3[idx - 250];
            else if (idx < 292) v = bx3[idx - 290];
            wreg[r] = v;
        }
#pragma unroll
        for (int i = 0; i < 140; ++i) {        // pin Wx2 rows 39..45
            wv[i] = Wx2[780 + i];
            asm volatile("" : "+v"(wv[i]));
        }
    }
    __syncthreads();   // startup barrier: keep the full drain (global loads)

    const int lw = is_f ? wid : (wid - 2);
    const int lpA = lw * 128 + lane;
    const int lpB = lpA + 64;
    const int pA  = blockIdx.x * 256 + lpA;
    const int pB  = blockIdx.x * 256 + lpB;

    float hA0 = 0.f, hA1 = 0.f, hB0 = 0.f, hB1 = 0.f;
    if (is_f) {
        hA0 = w[2 * pA]; hA1 = w[2 * pA + 1];
        hB0 = w[2 * pB]; hB1 = w[2 * pB + 1];
    }
    float2* __restrict__ orowA = out + (size_t)pA * (size_t)T;
    float2* __restrict__ orowB = out + (size_t)pB * (size_t)T;

    for (int t = 0; t <= T; ++t) {
        if (is_f) {
            if (t < T) {
                // ===== F: h = lrelu3(h), 2 points, broadcasts shared =====
                float a1A[50], a1B[50];
#pragma unroll
                for (int j = 0; j < 50; ++j) {
                    const float s0 = WQ(j), s1 = WQ(50 + j), sb = WQ(100 + j);
                    a1A[j] = lrelu(fmaf(hA0, s0, fmaf(hA1, s1, sb)));
                    a1B[j] = lrelu(fmaf(hB0, s0, fmaf(hB1, s1, sb)));
                }
                float accA[20], accB[20];
#pragma unroll
                for (int c = 0; c < 20; ++c) {
                    const float bv = WQ(270 + c);
                    accA[c] = bv; accB[c] = bv;
                }
#pragma unroll
                for (int k = 0; k < 37; ++k) {          // rows 0..36 via LDS
                    const float akA = a1A[k], akB = a1B[k];
#pragma unroll
                    for (int c = 0; c < 5; ++c) {
                        const float4 v = sW2h[k * 5 + c];
                        accA[4*c+0] = fmaf(akA, v.x, accA[4*c+0]);
                        accA[4*c+1] = fmaf(akA, v.y, accA[4*c+1]);
                        accA[4*c+2] = fmaf(akA, v.z, accA[4*c+2]);
                        accA[4*c+3] = fmaf(akA, v.w, accA[4*c+3]);
                        accB[4*c+0] = fmaf(akB, v.x, accB[4*c+0]);
                        accB[4*c+1] = fmaf(akB, v.y, accB[4*c+1]);
                        accB[4*c+2] = fmaf(akB, v.z, accB[4*c+2]);
                        accB[4*c+3] = fmaf(akB, v.w, accB[4*c+3]);
                    }
                }
#pragma unroll
                for (int k = 37; k < 44; ++k) {         // rows 37..43 via pin
                    const float akA = a1A[k], akB = a1B[k];
#pragma unroll
                    for (int c = 0; c < 20; ++c) {
                        const float wvv = wv[(k - 37) * 20 + c];
                        accA[c] = fmaf(akA, wvv, accA[c]);
                        accB[c] = fmaf(akB, wvv, accB[c]);
                    }
                }
#pragma unroll
                for (int k = 44; k < 50; ++k) {         // rows 44..49 via RL
                    const float akA = a1A[k], akB = a1B[k];
#pragma unroll
                    for (int c = 0; c < 20; ++c) {
                        const float wvv = WQ(150 + (k - 44) * 20 + c);
                        accA[c] = fmaf(akA, wvv, accA[c]);
                        accB[c] = fmaf(akB, wvv, accB[c]);
                    }
                }
                float zA0 = WQ(330), zA1 = WQ(331);
                float zB0 = zA0, zB1 = zA1;
#pragma unroll
                for (int k = 0; k < 20; ++k) {
                    const float wx = WQ(290 + 2 * k), wy = WQ(291 + 2 * k);
                    const float eA = lrelu(accA[k]), eB = lrelu(accB[k]);
                    zA0 = fmaf(eA, wx, zA0); zA1 = fmaf(eA, wy, zA1);
                    zB0 = fmaf(eB, wx, zB0); zB1 = fmaf(eB, wy, zB1);
                }
                hA0 = lrelu(zA0); hA1 = lrelu(zA1);
                hB0 = lrelu(zB0); hB1 = lrelu(zB1);

                hbuf[t & 1][lpA] = make_float2(hA0, hA1);
                hbuf[t & 1][lpB] = make_float2(hB0, hB1);
            }
        } else {
            if (t > 0) {
                // ===== X: x_s = sig3(h_s), s = t-1, 2 points =====
                const int s = t - 1;
                const float2 hvA = hbuf[s & 1][lpA];
                const float2 hvB = hbuf[s & 1][lpB];

                float accA[20], accB[20];
#pragma unroll
                for (int c = 0; c < 20; ++c) {
                    const float bv = WQ(230 + c);
                    accA[c] = bv; accB[c] = bv;
                }
#pragma unroll
                for (int k = 0; k < 50; ++k) {
                    // Wx1-trip via RL (off the binding LDS pipe)
                    const float s0 = WQ(k), s1 = WQ(50 + k), sb = WQ(100 + k);
                    const float xkA = sigf(fmaf(hvA.x, s0, fmaf(hvA.y, s1, sb)));
                    const float xkB = sigf(fmaf(hvB.x, s0, fmaf(hvB.y, s1, sb)));
                    if (k < 39) {                        // rows 0..38 via LDS
#pragma unroll
                        for (int c = 0; c < 5; ++c) {
                            const float4 v = sW2x[k * 5 + c];
                            accA[4*c+0] = fmaf(xkA, v.x, accA[4*c+0]);
                            accA[4*c+1] = fmaf(xkA, v.y, accA[4*c+1]);
                            accA[4*c+2] = fmaf(xkA, v.z, accA[4*c+2]);
                            accA[4*c+3] = fmaf(xkA, v.w, accA[4*c+3]);
                            accB[4*c+0] = fmaf(xkB, v.x, accB[4*c+0]);
                            accB[4*c+1] = fmaf(xkB, v.y, accB[4*c+1]);
                            accB[4*c+2] = fmaf(xkB, v.z, accB[4*c+2]);
                            accB[4*c+3] = fmaf(xkB, v.w, accB[4*c+3]);
                        }
                    } else if (k < 46) {                 // rows 39..45 via pin
#pragma unroll
                        for (int c = 0; c < 20; ++c) {
                            const float wvv = wv[(k - 39) * 20 + c];
                            accA[c] = fmaf(xkA, wvv, accA[c]);
                            accB[c] = fmaf(xkB, wvv, accB[c]);
                        }
                    } else {                             // rows 46..49 via RL
#pragma unroll
                        for (int c = 0; c < 20; ++c) {
                            const float wvv = WQ(150 + (k - 46) * 20 + c);
                            accA[c] = fmaf(xkA, wvv, accA[c]);
                            accB[c] = fmaf(xkB, wvv, accB[c]);
                        }
                    }
                }
                float zA0 = WQ(290), zA1 = WQ(291);
                float zB0 = zA0, zB1 = zA1;
#pragma unroll
                for (int k = 0; k < 20; ++k) {
                    const float wx = WQ(250 + 2 * k), wy = WQ(251 + 2 * k);
                    const float eA = sigf(accA[k]), eB = sigf(accB[k]);
                    zA0 = fmaf(eA, wx, zA0); zA1 = fmaf(eA, wy, zA1);
                    zB0 = fmaf(eB, wx, zB0); zB1 = fmaf(eB, wy, zB1);
                }
                orowA[s] = make_float2(sigf(zA0), sigf(zA1));
                orowB[s] = make_float2(sigf(zB0), sigf(zB1));
            }
        }
        // lgkmcnt-only barrier: orders hbuf handoff; global stores float.
        lds_barrier();
    }
}

extern "C" void kernel_launch(void* const* d_in, const int* in_sizes, int n_in,
                              void* d_out, int out_size, void* d_ws, size_t ws_size,
                              hipStream_t stream)
{
    const float* w   = (const float*)d_in[0];
    const float* Wh1 = (const float*)d_in[1];
    const float* bh1 = (const float*)d_in[2];
    const float* Wh2 = (const float*)d_in[3];
    const float* bh2 = (const float*)d_in[4];
    const float* Wh3 = (const float*)d_in[5];
    const float* bh3 = (const float*)d_in[6];
    const float* Wx1 = (const float*)d_in[7];
    const float* bx1 = (const float*)d_in[8];
    const float* Wx2 = (const float*)d_in[9];
    const float* bx2 = (const float*)d_in[10];
    const float* Wx3 = (const float*)d_in[11];
    const float* bx3 = (const float*)d_in[12];

    const int B = in_sizes[0] / 2;        // 65536 (divisible by 256)
    const int T = out_size / (B * 2);     // 512

    pc13_kernel<<<B / 256, 256, 0, stream>>>(
        w, Wh1, bh1, Wh2, bh2, Wh3, bh3,
        Wx1, bx1, Wx2, bx2, Wx3, bx3,
        (float2*)d_out, B, T);
}